// Round 9
// baseline (276.125 us; speedup 1.0000x reference)
//
#include <hip/hip_runtime.h>

typedef __bf16 bf16;
typedef __bf16 bf16x4 __attribute__((ext_vector_type(4)));
typedef __bf16 bf16x8 __attribute__((ext_vector_type(8)));
typedef float  f32x4  __attribute__((ext_vector_type(4)));
typedef float  f32x16 __attribute__((ext_vector_type(16)));

#define GLDS16(gsrc, ldst)                                                    \
  __builtin_amdgcn_global_load_lds(                                          \
      (const __attribute__((address_space(1))) void*)(gsrc),                 \
      (__attribute__((address_space(3))) void*)(ldst), 16, 0, 0)

#define MFMA16(a, b, c) __builtin_amdgcn_mfma_f32_16x16x32_bf16((a), (b), (c), 0, 0, 0)
#define MFMA32(a, b, c) __builtin_amdgcn_mfma_f32_32x32x16_bf16((a), (b), (c), 0, 0, 0)
// exchange a's hi-32-lane half with b's lo-32-lane half (gfx950)
#define PLSWAP(a, b) asm volatile("v_permlane32_swap_b32 %0, %1" : "+v"(a), "+v"(b))

__device__ inline unsigned pk2(float a, float b) {
  union { bf16 h[2]; unsigned u; } t;
  t.h[0] = (bf16)a; t.h[1] = (bf16)b;
  return t.u;
}

// ---------------- f32 -> bf16 convert (vectorized x4) ----------------
__global__ __launch_bounds__(256) void cvt_kernel(const float* __restrict__ in,
                                                  bf16* __restrict__ out, int n4) {
  int i = blockIdx.x * 256 + threadIdx.x;
  if (i >= n4) return;
  f32x4 f = *(const f32x4*)(in + (size_t)i * 4);
  bf16x4 b;
#pragma unroll
  for (int j = 0; j < 4; ++j) b[j] = (bf16)f[j];
  *(bf16x4*)(out + (size_t)i * 4) = b;
}

// ---------------- C = A * B^T  (A: MxK, B: NxK row-major, bf16 MFMA) -------
// ROPE: fused rotary epilogue for the QKV projection. Each wave's 64-col span
// is exactly one head (n0 mult of 128, wc*64 aligned), so the d<->d+32 partner
// is acc[mt][nt^2][r] in-lane. q heads (hb<32): scale = 0.125*log2e (exp2-
// domain softmax); k heads (32..39): scale 1; v heads (40..47): passthrough.
template <typename OutT, bool ROPE>
__global__ __launch_bounds__(256) void gemm_bt(const bf16* __restrict__ A,
                                               const bf16* __restrict__ Bm,
                                               OutT* __restrict__ C,
                                               int M, int N, int K,
                                               const float* __restrict__ cosb,
                                               const float* __restrict__ sinb) {
  __shared__ bf16 a_lds[128 * 32];
  __shared__ bf16 b_lds[128 * 32];
  const int tid = threadIdx.x;
  const int w = tid >> 6, lane = tid & 63;
  const int lr = lane & 15, lg = lane >> 4;
  const int wr = w >> 1, wc = w & 1;
  const int m0 = blockIdx.y * 128, n0 = blockIdx.x * 128;

  f32x4 acc[4][4];
#pragma unroll
  for (int i = 0; i < 4; ++i)
#pragma unroll
    for (int j = 0; j < 4; ++j) acc[i][j] = f32x4{0.f, 0.f, 0.f, 0.f};

  for (int kt = 0; kt < K; kt += 32) {
#pragma unroll
    for (int i = 0; i < 2; ++i) {
      int c = tid + 256 * i;
      int row = c >> 2, kc = c & 3;
      GLDS16(A  + (size_t)(m0 + row) * K + kt + kc * 8, &a_lds[(w * 64 + 256 * i) * 8]);
      GLDS16(Bm + (size_t)(n0 + row) * K + kt + kc * 8, &b_lds[(w * 64 + 256 * i) * 8]);
    }
    __syncthreads();
    bf16x8 af[4], bfr[4];
#pragma unroll
    for (int t = 0; t < 4; ++t) {
      af[t]  = *(const bf16x8*)&a_lds[(wr * 64 + t * 16 + lr) * 32 + lg * 8];
      bfr[t] = *(const bf16x8*)&b_lds[(wc * 64 + t * 16 + lr) * 32 + lg * 8];
    }
#pragma unroll
    for (int mt = 0; mt < 4; ++mt)
#pragma unroll
      for (int nt = 0; nt < 4; ++nt)
        acc[mt][nt] = MFMA16(af[mt], bfr[nt], acc[mt][nt]);
    __syncthreads();
  }

  const int hb = (n0 + wc * 64) >> 6;                 // head block (wave-uniform)
  const bool dorope = ROPE && (hb < 40);
  const float rsc = (ROPE && hb < 32) ? 0.18033688011112042f : 1.0f;

#pragma unroll
  for (int mt = 0; mt < 4; ++mt)
#pragma unroll
    for (int r = 0; r < 4; ++r) {
      int mm = m0 + wr * 64 + mt * 16 + 4 * lg + r;   // C/D: row = 4*(l>>4)+reg
      float ov[4];
      if (dorope) {
        int l = mm & 2047;
        const float* cp = cosb + l * 64 + lr;
        const float* sp = sinb + l * 64 + lr;
        float a0 = acc[mt][0][r], a1 = acc[mt][1][r];
        float a2 = acc[mt][2][r], a3 = acc[mt][3][r];
        ov[0] = (a0 * cp[0]  - a2 * sp[0])  * rsc;    // d = lr      (<32)
        ov[1] = (a1 * cp[16] - a3 * sp[16]) * rsc;    // d = 16+lr   (<32)
        ov[2] = (a2 * cp[32] + a0 * sp[32]) * rsc;    // d = 32+lr
        ov[3] = (a3 * cp[48] + a1 * sp[48]) * rsc;    // d = 48+lr
      } else {
#pragma unroll
        for (int nt = 0; nt < 4; ++nt) ov[nt] = acc[mt][nt][r];
      }
#pragma unroll
      for (int nt = 0; nt < 4; ++nt) {
        int nn = n0 + wc * 64 + nt * 16 + lr;         // col = l&15
        C[(size_t)mm * N + nn] = (OutT)ov[nt];
      }
    }
}

// ---------------- causal GQA flash attention (swapped QK^T, 32x32) ----------
// 1024 blocks x 256 thr (4 waves); block owns 128 q rows (wave w: 32 rows).
// Latin-square q-tile assignment: CU c hosts {c,c+256,c+512,c+768} (round-robin
// placement) -> same bh, u-set summing to 30 -> every CU runs exactly 68
// kv-tile iterations. Softmax in exp2 domain, fully in-register (swapped
// mfma(K,Q)); depth-5 parallel max/sum trees; defer-max; V^T kv-group
// XOR-swizzled; K chunk-XOR swizzled. T5 setprio around MFMA clusters.
__global__ __launch_bounds__(256, 4) void attn_kernel(const bf16* __restrict__ q,
                                                      const bf16* __restrict__ k,
                                                      const bf16* __restrict__ v,
                                                      bf16* __restrict__ o) {
  constexpr int L = 2048;
  constexpr int QS = 3072;   // qkv row stride (elements)
  constexpr int OS = 2048;   // o row stride
  const int id = blockIdx.x;
  const int bh = id & 63;
  const int pq = (id >> 6) & 3;
  const int gq = id >> 8;
  // nibble table rows {15,0,14,1},{13,2,12,3},{11,4,10,5},{9,6,8,7}
  const int u  = (int)((0x78695A4B3C2D1E0FULL >> (4 * ((pq << 2) | gq))) & 15);
  const int q0 = u * 128;
  const int b = bh >> 5, h = bh & 31, g = h >> 2;
  const int tid = threadIdx.x;
  const int w = tid >> 6, lane = tid & 63;
  const int lc = lane & 31;        // q column (QK) / d column (PV)
  const int H  = lane >> 5;
  const int off4 = 4 * H;
  const int qw = q0 + w * 32;
  const int qg = qw + lc;          // this lane's q row (global)

  __shared__ bf16     k_lds[2][64 * 64];   // [kv][d], 16B-chunk XOR-swizzled
  __shared__ unsigned vt_w[2][64 * 36];    // V^T [d][kv-pair], stride 36, kv-grp^c8

  // Q B-frag: col=q=lc, k(d) = 16s + 8H + j
  bf16x8 qf[4];
  {
    const bf16* qrow = q + (size_t)(b * L + qg) * QS + h * 64 + 8 * H;
#pragma unroll
    for (int s = 0; s < 4; ++s) qf[s] = *(const bf16x8*)(qrow + 16 * s);
  }

  f32x16 acc0, acc1;
#pragma unroll
  for (int r = 0; r < 16; ++r) { acc0[r] = 0.f; acc1[r] = 0.f; }
  float m_run = -1e30f, l_run = 0.f;

  uint4 uv[2];  // in-flight V (issue-early / write-late)

  auto stageK = [&](int kv0, int buf) {
#pragma unroll
    for (int i = 0; i < 2; ++i) {
      int c = tid + 256 * i;
      int kvr = c >> 3, c8 = c & 7;
      GLDS16(k + (size_t)(b * L + kv0 + kvr) * QS + g * 64 + ((c8 ^ (kvr & 7)) * 8),
             &k_lds[buf][(w * 64 + 256 * i) * 8]);
    }
  };
  auto loadV = [&](int kv0) {
#pragma unroll
    for (int i = 0; i < 2; ++i) {
      int c = tid + 256 * i;
      uv[i] = *(const uint4*)(v + (size_t)(b * L + kv0 + (c >> 3)) * QS + g * 64 + (c & 7) * 8);
    }
  };
  auto writeV = [&](int buf) {
#pragma unroll
    for (int i = 0; i < 2; ++i) {
      int c = tid + 256 * i;
      int kvr = c >> 3, c8 = c & 7;
      unsigned o0 = uv[i].x, o1 = uv[i].y, o2 = uv[i].z, o3 = uv[i].w;
      unsigned p0 = (unsigned)__shfl_xor((int)o0, 8);
      unsigned p1 = (unsigned)__shfl_xor((int)o1, 8);
      unsigned p2 = (unsigned)__shfl_xor((int)o2, 8);
      unsigned p3 = (unsigned)__shfl_xor((int)o3, 8);
      int pr = kvr & 1, kvw = kvr >> 1;
      int wbase = (kvw & 3) + 4 * ((kvw >> 2) ^ c8);   // kv-group XOR c8
#pragma unroll
      for (int jj = 0; jj < 4; ++jj) {
        unsigned ow = (jj >> 1) ? (pr ? o3 : o1) : (pr ? o2 : o0);
        unsigned pw = (jj >> 1) ? (pr ? p3 : p1) : (pr ? p2 : p0);
        unsigned oe = (jj & 1) ? (ow >> 16) : (ow & 0xFFFFu);
        unsigned pe = (jj & 1) ? (pw >> 16) : (pw & 0xFFFFu);
        unsigned lo = pr ? pe : oe;   // even kv
        unsigned hi = pr ? oe : pe;   // odd kv
        int d = 8 * c8 + 4 * pr + jj;
        vt_w[buf][d * 36 + wbase] = lo | (hi << 16);
      }
    }
  };

  const int nt = 2 * u + 2;   // kv tiles 0 .. q0+64
  stageK(0, 0);
  loadV(0);
  writeV(0);
  __syncthreads();

  for (int it = 0; it < nt; ++it) {
    const int cur = it & 1;
    const int kv0 = it * 64;
    const bool notlast = (it + 1 < nt);
    if (notlast) {
      stageK(kv0 + 64, cur ^ 1);
      loadV(kv0 + 64);
    }

    if (kv0 <= qw + 31) {   // wave-uniform skip of fully-masked tiles
      // ---- S = K Q (A=K rows=kv, B=Q cols=q), exp2 domain ----
      f32x16 p0, p1;
#pragma unroll
      for (int r = 0; r < 16; ++r) { p0[r] = 0.f; p1[r] = 0.f; }
      __builtin_amdgcn_s_setprio(1);
#pragma unroll
      for (int s = 0; s < 4; ++s) {
        int ch = ((2 * s + H) ^ (lc & 7)) * 8;
        bf16x8 kf0 = *(const bf16x8*)&k_lds[cur][lc * 64 + ch];
        bf16x8 kf1 = *(const bf16x8*)&k_lds[cur][(32 + lc) * 64 + ch];
        p0 = MFMA32(kf0, qf[s], p0);
        p1 = MFMA32(kf1, qf[s], p1);
      }
      __builtin_amdgcn_s_setprio(0);

      // ---- causal mask: D row=kv=(r&3)+8(r>>2)+4H, col=q=lc ----
      if (kv0 + 63 > qw) {
#pragma unroll
        for (int r = 0; r < 16; ++r) {
          int kvl = kv0 + (r & 3) + 8 * (r >> 2) + off4;
          if (kvl > qg)      p0[r] = -1e30f;
          if (kvl + 32 > qg) p1[r] = -1e30f;
        }
      }

      // ---- online softmax: depth-5 parallel max tree (was 31-deep serial) ----
      float tm[16];
#pragma unroll
      for (int i = 0; i < 16; ++i) tm[i] = fmaxf(p0[i], p1[i]);
#pragma unroll
      for (int st = 8; st > 0; st >>= 1)
#pragma unroll
        for (int i = 0; i < st; ++i) tm[i] = fmaxf(tm[i], tm[i + st]);
      float mt = fmaxf(tm[0], __shfl_xor(tm[0], 32));

      const int defer = __all(mt <= m_run + 11.0f);   // ~8 nats in log2 domain
      float alpha = 1.f;
      if (!defer) {
        float mn = fmaxf(m_run, mt);
        alpha = exp2f(m_run - mn);
        m_run = mn;
      }
#pragma unroll
      for (int r = 0; r < 16; ++r) {
        p0[r] = exp2f(p0[r] - m_run);
        p1[r] = exp2f(p1[r] - m_run);
      }
      // depth-5 parallel sum tree
      float ts[16];
#pragma unroll
      for (int i = 0; i < 16; ++i) ts[i] = p0[i] + p1[i];
#pragma unroll
      for (int st = 8; st > 0; st >>= 1)
#pragma unroll
        for (int i = 0; i < st; ++i) ts[i] += ts[i + st];
      float ls = ts[0] + __shfl_xor(ts[0], 32);
      l_run = l_run * alpha + ls;
      if (!defer) {
#pragma unroll
        for (int r = 0; r < 16; ++r) {
          float aq = __shfl(alpha, ((r & 3) + 8 * (r >> 2)) + off4);
          acc0[r] *= aq;
          acc1[r] *= aq;
        }
      }

      // ---- P -> bf16 A-frags: pack pairs, permlane32_swap redistributes ----
      unsigned A[16];
#pragma unroll
      for (int i = 0; i < 8; ++i) {
        A[i]     = pk2(p0[2 * i], p0[2 * i + 1]);
        A[8 + i] = pk2(p1[2 * i], p1[2 * i + 1]);
      }
#pragma unroll
      for (int base = 0; base < 16; base += 4) {
        PLSWAP(A[base],     A[base + 2]);
        PLSWAP(A[base + 1], A[base + 3]);
      }

      // ---- O += P V  (A=P rows=q, B=V cols=d) ----
      __builtin_amdgcn_s_setprio(1);
#pragma unroll
      for (int sp = 0; sp < 4; ++sp) {
        union { unsigned u[4]; bf16x8 v8; } pa;
#pragma unroll
        for (int jx = 0; jx < 4; ++jx) pa.u[jx] = A[4 * sp + jx];
        int g0 = (2 * sp + H) ^ (lc >> 3);
        int g1 = (2 * sp + H) ^ (4 + (lc >> 3));
        bf16x8 vf0 = *(const bf16x8*)&vt_w[cur][lc * 36 + 4 * g0];
        bf16x8 vf1 = *(const bf16x8*)&vt_w[cur][(32 + lc) * 36 + 4 * g1];
        acc0 = MFMA32(pa.v8, vf0, acc0);
        acc1 = MFMA32(pa.v8, vf1, acc1);
      }
      __builtin_amdgcn_s_setprio(0);
    }

    if (notlast) writeV(cur ^ 1);
    __syncthreads();
  }

  // ---- epilogue: divide by l (per-q, via shfl) and store ----
#pragma unroll
  for (int r = 0; r < 16; ++r) {
    int qrow = (r & 3) + 8 * (r >> 2) + off4;
    float lq = __shfl(l_run, qrow);
    float inv = 1.f / lq;
    size_t orow = (size_t)(b * L + qw + qrow) * OS + h * 64;
    o[orow + lc]      = (bf16)(acc0[r] * inv);
    o[orow + 32 + lc] = (bf16)(acc1[r] * inv);
  }
}

extern "C" void kernel_launch(void* const* d_in, const int* in_sizes, int n_in,
                              void* d_out, int out_size, void* d_ws, size_t ws_size,
                              hipStream_t stream) {
  (void)in_sizes; (void)n_in; (void)out_size; (void)ws_size;
  const float* x    = (const float*)d_in[0];
  const float* cosb = (const float*)d_in[1];
  const float* sinb = (const float*)d_in[2];
  const float* Wq   = (const float*)d_in[3];
  const float* Wk   = (const float*)d_in[4];
  const float* Wv   = (const float*)d_in[5];
  const float* Wo   = (const float*)d_in[6];

  constexpr int B = 2, L = 2048, D = 2048, H = 32, G = 8;
  constexpr int M = B * L;           // 4096
  constexpr int DKV = G * 64;        // 512
  constexpr int NQKV = D + 2 * DKV;  // 3072

  char* p = (char*)d_ws;
  bf16* xb   = (bf16*)p; p += (size_t)M * D * 2;
  bf16* wqkv = (bf16*)p; p += (size_t)NQKV * D * 2;
  bf16* wob  = (bf16*)p; p += (size_t)D * D * 2;
  bf16* qkv  = (bf16*)p; p += (size_t)M * NQKV * 2;
  bf16* ob   = xb;  // xb dead after QKV GEMM

  auto cvt = [&](const float* src, bf16* dst, size_t n) {
    int n4 = (int)(n / 4);
    cvt_kernel<<<(n4 + 255) / 256, 256, 0, stream>>>(src, dst, n4);
  };
  cvt(x,  xb,                           (size_t)M * D);
  cvt(Wq, wqkv,                         (size_t)D * D);
  cvt(Wk, wqkv + (size_t)D * D,         (size_t)DKV * D);
  cvt(Wv, wqkv + (size_t)(D + DKV) * D, (size_t)DKV * D);
  cvt(Wo, wob,                          (size_t)D * D);

  // fused QKV projection + RoPE epilogue (q scale = 0.125*log2e for exp2 softmax)
  gemm_bt<bf16, true><<<dim3(NQKV / 128, M / 128), 256, 0, stream>>>(
      xb, wqkv, qkv, M, NQKV, D, cosb, sinb);

  attn_kernel<<<dim3(1024), 256, 0, stream>>>(qkv, qkv + D, qkv + D + DKV, ob);

  gemm_bt<float, false><<<dim3(D / 128, M / 128), 256, 0, stream>>>(
      ob, wob, (float*)d_out, M, D, D, nullptr, nullptr);
}

// Round 10
// 241.973 us; speedup vs baseline: 1.1411x; 1.1411x over previous
//
#include <hip/hip_runtime.h>

typedef __bf16 bf16;
typedef __bf16 bf16x4 __attribute__((ext_vector_type(4)));
typedef __bf16 bf16x8 __attribute__((ext_vector_type(8)));
typedef float  f32x4  __attribute__((ext_vector_type(4)));
typedef float  f32x16 __attribute__((ext_vector_type(16)));

#define GLDS16(gsrc, ldst)                                                    \
  __builtin_amdgcn_global_load_lds(                                          \
      (const __attribute__((address_space(1))) void*)(gsrc),                 \
      (__attribute__((address_space(3))) void*)(ldst), 16, 0, 0)

#define MFMA16(a, b, c) __builtin_amdgcn_mfma_f32_16x16x32_bf16((a), (b), (c), 0, 0, 0)
#define MFMA32(a, b, c) __builtin_amdgcn_mfma_f32_32x32x16_bf16((a), (b), (c), 0, 0, 0)
// exchange a's hi-32-lane half with b's lo-32-lane half (gfx950)
#define PLSWAP(a, b) asm volatile("v_permlane32_swap_b32 %0, %1" : "+v"(a), "+v"(b))

__device__ inline unsigned pk2(float a, float b) {
  union { bf16 h[2]; unsigned u; } t;
  t.h[0] = (bf16)a; t.h[1] = (bf16)b;
  return t.u;
}

// ---------------- f32 -> bf16 convert (vectorized x4) ----------------
__global__ __launch_bounds__(256) void cvt_kernel(const float* __restrict__ in,
                                                  bf16* __restrict__ out, int n4) {
  int i = blockIdx.x * 256 + threadIdx.x;
  if (i >= n4) return;
  f32x4 f = *(const f32x4*)(in + (size_t)i * 4);
  bf16x4 b;
#pragma unroll
  for (int j = 0; j < 4; ++j) b[j] = (bf16)f[j];
  *(bf16x4*)(out + (size_t)i * 4) = b;
}

// ---------------- V -> swizzled V^T global ([b][g][64][L]) ----------------
// Within each 64-kv tile, stored chunk sc (8 elems) of row d holds source kv
// chunk sc^(d&7) — so attention can stage rows linearly with global_load_lds
// and read b128 at chunk (2sp+H)^(d&7), conflict-free (same pattern as K).
// Internal LDS: t[d*64 + (kv ^ 8*((d>>3)^(d&7)))] — writes 2-way (free),
// reads b128 16B-aligned at the 8-lane/quad floor (derivation in journal).
__global__ __launch_bounds__(256) void vtr_kernel(const bf16* __restrict__ v,
                                                  bf16* __restrict__ vt) {
  constexpr int L = 2048, QS = 3072;
  const int kv0 = blockIdx.x * 64;
  const int bg = blockIdx.y;            // b*8+g
  const int tid = threadIdx.x;
  __shared__ bf16 t[64 * 64];

#pragma unroll
  for (int i = 0; i < 2; ++i) {
    int c = tid + 256 * i;
    int kv = c >> 3, e = c & 7;         // row kv, d-chunk e (d = 8e+j)
    bf16x8 row = *(const bf16x8*)(v + (size_t)((bg >> 3) * L + kv0 + kv) * QS +
                                  (bg & 7) * 64 + e * 8);
#pragma unroll
    for (int j = 0; j < 8; ++j)
      t[(8 * e + j) * 64 + (kv ^ (8 * (e ^ j)))] = row[j];
  }
  __syncthreads();

  const int d = tid >> 2, c4 = tid & 3;
  bf16* orow = vt + ((size_t)bg * 64 + d) * L + kv0;
#pragma unroll
  for (int dl = 0; dl < 2; ++dl) {
    int sc = 2 * c4 + dl;                                  // stored chunk
    bf16x8 ch = *(const bf16x8*)&t[d * 64 + 8 * (sc ^ (d >> 3))];
    *(bf16x8*)(orow + 8 * sc) = ch;
  }
}

// ---------------- C = A * B^T  (A: MxK, B: NxK row-major, bf16 MFMA) -------
// ROPE: fused rotary epilogue for the QKV projection (see R9 notes).
template <typename OutT, bool ROPE>
__global__ __launch_bounds__(256) void gemm_bt(const bf16* __restrict__ A,
                                               const bf16* __restrict__ Bm,
                                               OutT* __restrict__ C,
                                               int M, int N, int K,
                                               const float* __restrict__ cosb,
                                               const float* __restrict__ sinb) {
  __shared__ bf16 a_lds[128 * 32];
  __shared__ bf16 b_lds[128 * 32];
  const int tid = threadIdx.x;
  const int w = tid >> 6, lane = tid & 63;
  const int lr = lane & 15, lg = lane >> 4;
  const int wr = w >> 1, wc = w & 1;
  const int m0 = blockIdx.y * 128, n0 = blockIdx.x * 128;

  f32x4 acc[4][4];
#pragma unroll
  for (int i = 0; i < 4; ++i)
#pragma unroll
    for (int j = 0; j < 4; ++j) acc[i][j] = f32x4{0.f, 0.f, 0.f, 0.f};

  for (int kt = 0; kt < K; kt += 32) {
#pragma unroll
    for (int i = 0; i < 2; ++i) {
      int c = tid + 256 * i;
      int row = c >> 2, kc = c & 3;
      GLDS16(A  + (size_t)(m0 + row) * K + kt + kc * 8, &a_lds[(w * 64 + 256 * i) * 8]);
      GLDS16(Bm + (size_t)(n0 + row) * K + kt + kc * 8, &b_lds[(w * 64 + 256 * i) * 8]);
    }
    __syncthreads();
    bf16x8 af[4], bfr[4];
#pragma unroll
    for (int t = 0; t < 4; ++t) {
      af[t]  = *(const bf16x8*)&a_lds[(wr * 64 + t * 16 + lr) * 32 + lg * 8];
      bfr[t] = *(const bf16x8*)&b_lds[(wc * 64 + t * 16 + lr) * 32 + lg * 8];
    }
#pragma unroll
    for (int mt = 0; mt < 4; ++mt)
#pragma unroll
      for (int nt = 0; nt < 4; ++nt)
        acc[mt][nt] = MFMA16(af[mt], bfr[nt], acc[mt][nt]);
    __syncthreads();
  }

  const int hb = (n0 + wc * 64) >> 6;                 // head block (wave-uniform)
  const bool dorope = ROPE && (hb < 40);
  const float rsc = (ROPE && hb < 32) ? 0.18033688011112042f : 1.0f;

#pragma unroll
  for (int mt = 0; mt < 4; ++mt)
#pragma unroll
    for (int r = 0; r < 4; ++r) {
      int mm = m0 + wr * 64 + mt * 16 + 4 * lg + r;   // C/D: row = 4*(l>>4)+reg
      float ov[4];
      if (dorope) {
        int l = mm & 2047;
        const float* cp = cosb + l * 64 + lr;
        const float* sp = sinb + l * 64 + lr;
        float a0 = acc[mt][0][r], a1 = acc[mt][1][r];
        float a2 = acc[mt][2][r], a3 = acc[mt][3][r];
        ov[0] = (a0 * cp[0]  - a2 * sp[0])  * rsc;
        ov[1] = (a1 * cp[16] - a3 * sp[16]) * rsc;
        ov[2] = (a2 * cp[32] + a0 * sp[32]) * rsc;
        ov[3] = (a3 * cp[48] + a1 * sp[48]) * rsc;
      } else {
#pragma unroll
        for (int nt = 0; nt < 4; ++nt) ov[nt] = acc[mt][nt][r];
      }
#pragma unroll
      for (int nt = 0; nt < 4; ++nt) {
        int nn = n0 + wc * 64 + nt * 16 + lr;         // col = l&15
        C[(size_t)mm * N + nn] = (OutT)ov[nt];
      }
    }
}

// ---------------- causal GQA flash attention (swapped QK^T, 32x32) ----------
// 1024 blocks x 256 thr (4 waves); block owns 128 q rows (wave w: 32 rows).
// Latin-square q-tile assignment (uniform 68 iters/CU under round-robin).
// K AND V^T both staged via global_load_lds from pre-swizzled global layouts
// (zero staging VALU). Softmax in exp2 domain, in-register, serial-chain
// reductions (R8 form — tree rewrite regressed, reverted). Defer-max.
__global__ __launch_bounds__(256, 4) void attn_kernel(const bf16* __restrict__ q,
                                                      const bf16* __restrict__ k,
                                                      const bf16* __restrict__ vtg,
                                                      bf16* __restrict__ o) {
  constexpr int L = 2048;
  constexpr int QS = 3072;   // qkv row stride (elements)
  constexpr int OS = 2048;   // o row stride
  const int id = blockIdx.x;
  const int bh = id & 63;
  const int pq = (id >> 6) & 3;
  const int gq = id >> 8;
  // nibble table rows {15,0,14,1},{13,2,12,3},{11,4,10,5},{9,6,8,7}
  const int u  = (int)((0x78695A4B3C2D1E0FULL >> (4 * ((pq << 2) | gq))) & 15);
  const int q0 = u * 128;
  const int b = bh >> 5, h = bh & 31, g = h >> 2;
  const int tid = threadIdx.x;
  const int w = tid >> 6, lane = tid & 63;
  const int lc = lane & 31;        // q column (QK) / d column (PV)
  const int H  = lane >> 5;
  const int off4 = 4 * H;
  const int qw = q0 + w * 32;
  const int qg = qw + lc;          // this lane's q row (global)

  __shared__ bf16 k_lds[2][64 * 64];   // [kv][d], 16B-chunk XOR-swizzled
  __shared__ bf16 vt_lds[2][64 * 64];  // V^T [d][kv], chunk-swizzled (from vtg)

  // Q B-frag: col=q=lc, k(d) = 16s + 8H + j
  bf16x8 qf[4];
  {
    const bf16* qrow = q + (size_t)(b * L + qg) * QS + h * 64 + 8 * H;
#pragma unroll
    for (int s = 0; s < 4; ++s) qf[s] = *(const bf16x8*)(qrow + 16 * s);
  }

  f32x16 acc0, acc1;
#pragma unroll
  for (int r = 0; r < 16; ++r) { acc0[r] = 0.f; acc1[r] = 0.f; }
  float m_run = -1e30f, l_run = 0.f;

  const bf16* vbase = vtg + (size_t)(b * 8 + g) * 64 * L;

  auto stageK = [&](int kv0, int buf) {
#pragma unroll
    for (int i = 0; i < 2; ++i) {
      int c = tid + 256 * i;
      int kvr = c >> 3, c8 = c & 7;
      GLDS16(k + (size_t)(b * L + kv0 + kvr) * QS + g * 64 + ((c8 ^ (kvr & 7)) * 8),
             &k_lds[buf][(w * 64 + 256 * i) * 8]);
    }
  };
  auto stageV = [&](int kv0, int buf) {
#pragma unroll
    for (int i = 0; i < 2; ++i) {
      int c = tid + 256 * i;
      GLDS16(vbase + (size_t)(c >> 3) * L + kv0 + (c & 7) * 8,
             &vt_lds[buf][(w * 64 + 256 * i) * 8]);
    }
  };

  const int nt = 2 * u + 2;   // kv tiles 0 .. q0+64
  stageK(0, 0);
  stageV(0, 0);
  __syncthreads();

  for (int it = 0; it < nt; ++it) {
    const int cur = it & 1;
    const int kv0 = it * 64;
    const bool notlast = (it + 1 < nt);
    if (notlast) {
      stageK(kv0 + 64, cur ^ 1);
      stageV(kv0 + 64, cur ^ 1);
    }

    if (kv0 <= qw + 31) {   // wave-uniform skip of fully-masked tiles
      // ---- S = K Q (A=K rows=kv, B=Q cols=q), exp2 domain ----
      f32x16 p0, p1;
#pragma unroll
      for (int r = 0; r < 16; ++r) { p0[r] = 0.f; p1[r] = 0.f; }
      __builtin_amdgcn_s_setprio(1);
#pragma unroll
      for (int s = 0; s < 4; ++s) {
        int ch = ((2 * s + H) ^ (lc & 7)) * 8;
        bf16x8 kf0 = *(const bf16x8*)&k_lds[cur][lc * 64 + ch];
        bf16x8 kf1 = *(const bf16x8*)&k_lds[cur][(32 + lc) * 64 + ch];
        p0 = MFMA32(kf0, qf[s], p0);
        p1 = MFMA32(kf1, qf[s], p1);
      }
      __builtin_amdgcn_s_setprio(0);

      // ---- causal mask: D row=kv=(r&3)+8(r>>2)+4H, col=q=lc ----
      if (kv0 + 63 > qw) {
#pragma unroll
        for (int r = 0; r < 16; ++r) {
          int kvl = kv0 + (r & 3) + 8 * (r >> 2) + off4;
          if (kvl > qg)      p0[r] = -1e30f;
          if (kvl + 32 > qg) p1[r] = -1e30f;
        }
      }

      // ---- online softmax, in-register (T12) + defer-max (T13) ----
      float mt = -1e30f;
#pragma unroll
      for (int r = 0; r < 16; ++r) mt = fmaxf(mt, fmaxf(p0[r], p1[r]));
      mt = fmaxf(mt, __shfl_xor(mt, 32));
      const int defer = __all(mt <= m_run + 11.0f);   // ~8 nats in log2 domain
      float alpha = 1.f;
      if (!defer) {
        float mn = fmaxf(m_run, mt);
        alpha = exp2f(m_run - mn);
        m_run = mn;
      }
      float ls = 0.f;
#pragma unroll
      for (int r = 0; r < 16; ++r) {
        p0[r] = exp2f(p0[r] - m_run);
        p1[r] = exp2f(p1[r] - m_run);
        ls += p0[r] + p1[r];
      }
      ls += __shfl_xor(ls, 32);
      l_run = l_run * alpha + ls;
      if (!defer) {
#pragma unroll
        for (int r = 0; r < 16; ++r) {
          float aq = __shfl(alpha, ((r & 3) + 8 * (r >> 2)) + off4);
          acc0[r] *= aq;
          acc1[r] *= aq;
        }
      }

      // ---- P -> bf16 A-frags: pack pairs, permlane32_swap redistributes ----
      unsigned A[16];
#pragma unroll
      for (int i = 0; i < 8; ++i) {
        A[i]     = pk2(p0[2 * i], p0[2 * i + 1]);
        A[8 + i] = pk2(p1[2 * i], p1[2 * i + 1]);
      }
#pragma unroll
      for (int base = 0; base < 16; base += 4) {
        PLSWAP(A[base],     A[base + 2]);
        PLSWAP(A[base + 1], A[base + 3]);
      }

      // ---- O += P V  (A=P rows=q, B=V^T cols=d) ----
      __builtin_amdgcn_s_setprio(1);
#pragma unroll
      for (int sp = 0; sp < 4; ++sp) {
        union { unsigned u[4]; bf16x8 v8; } pa;
#pragma unroll
        for (int jx = 0; jx < 4; ++jx) pa.u[jx] = A[4 * sp + jx];
        int ch = ((2 * sp + H) ^ (lc & 7)) * 8;
        bf16x8 vf0 = *(const bf16x8*)&vt_lds[cur][lc * 64 + ch];
        bf16x8 vf1 = *(const bf16x8*)&vt_lds[cur][(32 + lc) * 64 + ch];
        acc0 = MFMA32(pa.v8, vf0, acc0);
        acc1 = MFMA32(pa.v8, vf1, acc1);
      }
      __builtin_amdgcn_s_setprio(0);
    }

    __syncthreads();   // drains prefetch vmcnt; publishes next buffers
  }

  // ---- epilogue: divide by l (per-q, via shfl) and store ----
#pragma unroll
  for (int r = 0; r < 16; ++r) {
    int qrow = (r & 3) + 8 * (r >> 2) + off4;
    float lq = __shfl(l_run, qrow);
    float inv = 1.f / lq;
    size_t orow = (size_t)(b * L + qw + qrow) * OS + h * 64;
    o[orow + lc]      = (bf16)(acc0[r] * inv);
    o[orow + 32 + lc] = (bf16)(acc1[r] * inv);
  }
}

extern "C" void kernel_launch(void* const* d_in, const int* in_sizes, int n_in,
                              void* d_out, int out_size, void* d_ws, size_t ws_size,
                              hipStream_t stream) {
  (void)in_sizes; (void)n_in; (void)out_size; (void)ws_size;
  const float* x    = (const float*)d_in[0];
  const float* cosb = (const float*)d_in[1];
  const float* sinb = (const float*)d_in[2];
  const float* Wq   = (const float*)d_in[3];
  const float* Wk   = (const float*)d_in[4];
  const float* Wv   = (const float*)d_in[5];
  const float* Wo   = (const float*)d_in[6];

  constexpr int B = 2, L = 2048, D = 2048, H = 32, G = 8;
  constexpr int M = B * L;           // 4096
  constexpr int DKV = G * 64;        // 512
  constexpr int NQKV = D + 2 * DKV;  // 3072

  char* p = (char*)d_ws;
  bf16* xb   = (bf16*)p; p += (size_t)M * D * 2;
  bf16* wqkv = (bf16*)p; p += (size_t)NQKV * D * 2;
  bf16* wob  = (bf16*)p; p += (size_t)D * D * 2;
  bf16* qkv  = (bf16*)p; p += (size_t)M * NQKV * 2;
  bf16* vtg  = (bf16*)p; p += (size_t)B * G * 64 * L * 2;
  bf16* ob   = xb;  // xb dead after QKV GEMM

  auto cvt = [&](const float* src, bf16* dst, size_t n) {
    int n4 = (int)(n / 4);
    cvt_kernel<<<(n4 + 255) / 256, 256, 0, stream>>>(src, dst, n4);
  };
  cvt(x,  xb,                           (size_t)M * D);
  cvt(Wq, wqkv,                         (size_t)D * D);
  cvt(Wk, wqkv + (size_t)D * D,         (size_t)DKV * D);
  cvt(Wv, wqkv + (size_t)(D + DKV) * D, (size_t)DKV * D);
  cvt(Wo, wob,                          (size_t)D * D);

  // fused QKV projection + RoPE epilogue (q scale = 0.125*log2e for exp2 softmax)
  gemm_bt<bf16, true><<<dim3(NQKV / 128, M / 128), 256, 0, stream>>>(
      xb, wqkv, qkv, M, NQKV, D, cosb, sinb);

  // V -> swizzled V^T global (consumed by attention via global_load_lds)
  vtr_kernel<<<dim3(L / 64, B * G), 256, 0, stream>>>(qkv + D + DKV, vtg);

  attn_kernel<<<dim3(1024), 256, 0, stream>>>(qkv, qkv + D, vtg, ob);

  gemm_bt<float, false><<<dim3(D / 128, M / 128), 256, 0, stream>>>(
      ob, wob, (float*)d_out, M, D, D, nullptr, nullptr);
}

// Round 11
// 239.876 us; speedup vs baseline: 1.1511x; 1.0087x over previous
//
#include <hip/hip_runtime.h>

typedef __bf16 bf16;
typedef __bf16 bf16x4 __attribute__((ext_vector_type(4)));
typedef __bf16 bf16x8 __attribute__((ext_vector_type(8)));
typedef float  f32x4  __attribute__((ext_vector_type(4)));
typedef float  f32x16 __attribute__((ext_vector_type(16)));

#define GLDS16(gsrc, ldst)                                                    \
  __builtin_amdgcn_global_load_lds(                                          \
      (const __attribute__((address_space(1))) void*)(gsrc),                 \
      (__attribute__((address_space(3))) void*)(ldst), 16, 0, 0)

#define MFMA16(a, b, c) __builtin_amdgcn_mfma_f32_16x16x32_bf16((a), (b), (c), 0, 0, 0)
#define MFMA32(a, b, c) __builtin_amdgcn_mfma_f32_32x32x16_bf16((a), (b), (c), 0, 0, 0)
// exchange a's hi-32-lane half with b's lo-32-lane half (gfx950)
#define PLSWAP(a, b) asm volatile("v_permlane32_swap_b32 %0, %1" : "+v"(a), "+v"(b))

__device__ inline unsigned pk2(float a, float b) {
  union { bf16 h[2]; unsigned u; } t;
  t.h[0] = (bf16)a; t.h[1] = (bf16)b;
  return t.u;
}

// ---------------- fused f32 -> bf16 convert for all 5 inputs ----------------
// Region bounds in float4 units (compile-time, multiples of 256 -> wave-uniform).
__global__ __launch_bounds__(256) void cvt5_kernel(const float* __restrict__ x,
                                                   const float* __restrict__ wq,
                                                   const float* __restrict__ wk,
                                                   const float* __restrict__ wv,
                                                   const float* __restrict__ wo,
                                                   bf16* __restrict__ xb,
                                                   bf16* __restrict__ wqkv,
                                                   bf16* __restrict__ wob) {
  int i = blockIdx.x * 256 + threadIdx.x;
  const float* src; bf16* dst; int off;
  if (i < 2097152)      { src = x;  dst = xb;             off = i; }
  else if (i < 3145728) { src = wq; dst = wqkv;           off = i - 2097152; }
  else if (i < 3407872) { src = wk; dst = wqkv + 4194304; off = i - 3145728; }
  else if (i < 3670016) { src = wv; dst = wqkv + 5242880; off = i - 3407872; }
  else                  { src = wo; dst = wob;            off = i - 3670016; }
  f32x4 f = *(const f32x4*)(src + (size_t)off * 4);
  bf16x4 o4;
#pragma unroll
  for (int j = 0; j < 4; ++j) o4[j] = (bf16)f[j];
  *(bf16x4*)(dst + (size_t)off * 4) = o4;
}

// ---------------- V -> swizzled V^T global ([b][g][64][L]) ----------------
// Stored chunk sc of row d holds source kv chunk sc^(d&7) within each 64-kv
// tile, so attention stages rows linearly with global_load_lds and reads
// b128 conflict-free (same pattern as K).
__global__ __launch_bounds__(256) void vtr_kernel(const bf16* __restrict__ v,
                                                  bf16* __restrict__ vt) {
  constexpr int L = 2048, QS = 3072;
  const int kv0 = blockIdx.x * 64;
  const int bg = blockIdx.y;            // b*8+g
  const int tid = threadIdx.x;
  __shared__ bf16 t[64 * 64];

#pragma unroll
  for (int i = 0; i < 2; ++i) {
    int c = tid + 256 * i;
    int kv = c >> 3, e = c & 7;         // row kv, d-chunk e (d = 8e+j)
    bf16x8 row = *(const bf16x8*)(v + (size_t)((bg >> 3) * L + kv0 + kv) * QS +
                                  (bg & 7) * 64 + e * 8);
#pragma unroll
    for (int j = 0; j < 8; ++j)
      t[(8 * e + j) * 64 + (kv ^ (8 * (e ^ j)))] = row[j];
  }
  __syncthreads();

  const int d = tid >> 2, c4 = tid & 3;
  bf16* orow = vt + ((size_t)bg * 64 + d) * L + kv0;
#pragma unroll
  for (int dl = 0; dl < 2; ++dl) {
    int sc = 2 * c4 + dl;                                  // stored chunk
    bf16x8 ch = *(const bf16x8*)&t[d * 64 + 8 * (sc ^ (d >> 3))];
    *(bf16x8*)(orow + 8 * sc) = ch;
  }
}

// ---------------- C = A * B^T  (A: MxK, B: NxK row-major, bf16 MFMA) -------
// m97-class structure (kept: explicit dbuf is documented-null on this shape).
// ROPE: fused rotary epilogue for the QKV projection.
template <typename OutT, bool ROPE>
__global__ __launch_bounds__(256) void gemm_bt(const bf16* __restrict__ A,
                                               const bf16* __restrict__ Bm,
                                               OutT* __restrict__ C,
                                               int M, int N, int K,
                                               const float* __restrict__ cosb,
                                               const float* __restrict__ sinb) {
  __shared__ bf16 a_lds[128 * 32];
  __shared__ bf16 b_lds[128 * 32];
  const int tid = threadIdx.x;
  const int w = tid >> 6, lane = tid & 63;
  const int lr = lane & 15, lg = lane >> 4;
  const int wr = w >> 1, wc = w & 1;
  const int m0 = blockIdx.y * 128, n0 = blockIdx.x * 128;

  f32x4 acc[4][4];
#pragma unroll
  for (int i = 0; i < 4; ++i)
#pragma unroll
    for (int j = 0; j < 4; ++j) acc[i][j] = f32x4{0.f, 0.f, 0.f, 0.f};

  for (int kt = 0; kt < K; kt += 32) {
#pragma unroll
    for (int i = 0; i < 2; ++i) {
      int c = tid + 256 * i;
      int row = c >> 2, kc = c & 3;
      GLDS16(A  + (size_t)(m0 + row) * K + kt + kc * 8, &a_lds[(w * 64 + 256 * i) * 8]);
      GLDS16(Bm + (size_t)(n0 + row) * K + kt + kc * 8, &b_lds[(w * 64 + 256 * i) * 8]);
    }
    __syncthreads();
    bf16x8 af[4], bfr[4];
#pragma unroll
    for (int t = 0; t < 4; ++t) {
      af[t]  = *(const bf16x8*)&a_lds[(wr * 64 + t * 16 + lr) * 32 + lg * 8];
      bfr[t] = *(const bf16x8*)&b_lds[(wc * 64 + t * 16 + lr) * 32 + lg * 8];
    }
#pragma unroll
    for (int mt = 0; mt < 4; ++mt)
#pragma unroll
      for (int nt = 0; nt < 4; ++nt)
        acc[mt][nt] = MFMA16(af[mt], bfr[nt], acc[mt][nt]);
    __syncthreads();
  }

  const int hb = (n0 + wc * 64) >> 6;                 // head block (wave-uniform)
  const bool dorope = ROPE && (hb < 40);
  const float rsc = (ROPE && hb < 32) ? 0.18033688011112042f : 1.0f;

#pragma unroll
  for (int mt = 0; mt < 4; ++mt)
#pragma unroll
    for (int r = 0; r < 4; ++r) {
      int mm = m0 + wr * 64 + mt * 16 + 4 * lg + r;   // C/D: row = 4*(l>>4)+reg
      float ov[4];
      if (dorope) {
        int l = mm & 2047;
        const float* cp = cosb + l * 64 + lr;
        const float* sp = sinb + l * 64 + lr;
        float a0 = acc[mt][0][r], a1 = acc[mt][1][r];
        float a2 = acc[mt][2][r], a3 = acc[mt][3][r];
        ov[0] = (a0 * cp[0]  - a2 * sp[0])  * rsc;
        ov[1] = (a1 * cp[16] - a3 * sp[16]) * rsc;
        ov[2] = (a2 * cp[32] + a0 * sp[32]) * rsc;
        ov[3] = (a3 * cp[48] + a1 * sp[48]) * rsc;
      } else {
#pragma unroll
        for (int nt = 0; nt < 4; ++nt) ov[nt] = acc[mt][nt][r];
      }
#pragma unroll
      for (int nt = 0; nt < 4; ++nt) {
        int nn = n0 + wc * 64 + nt * 16 + lr;         // col = l&15
        C[(size_t)mm * N + nn] = (OutT)ov[nt];
      }
    }
}

// ---------------- causal GQA flash attention (swapped QK^T, 32x32) ----------
// Split-KV: the diagonal-heavy q-tiles (u>=7) are split into two half-KV-range
// blocks writing UNNORMALIZED partials (bf16 O~, f32 m,l); comb_kernel merges.
// Max serial chain drops 32->16 kv-iters; 1600 longest-first blocks backfill
// dynamically. id<split_n: split block (bh=id&63, t=id>>6, u=15-(t>>1), s=t&1).
// id>=split_n: unsplit (u = umax - (e>>6)), full range, direct store.
__global__ __launch_bounds__(256, 4) void attn_kernel(const bf16* __restrict__ q,
                                                      const bf16* __restrict__ k,
                                                      const bf16* __restrict__ vtg,
                                                      bf16* __restrict__ o,
                                                      bf16* __restrict__ opart,
                                                      float* __restrict__ mpart,
                                                      float* __restrict__ lpart,
                                                      int split_n, int umax) {
  constexpr int L = 2048;
  constexpr int QS = 3072;   // qkv row stride (elements)
  constexpr int OS = 2048;   // o row stride
  const int id = blockIdx.x;
  int bh, u, ts, te, pidx;
  bool split;
  if (id < split_n) {
    bh = id & 63;
    int t = id >> 6;                  // 0..17
    u = 15 - (t >> 1);                // 15 down to 7 (longest first)
    int s = t & 1;
    ts = s * (u + 1);
    te = ts + (u + 1);
    pidx = (bh * 9 + (u - 7)) * 2 + s;
    split = true;
  } else {
    int e = id - split_n;
    bh = e & 63;
    u = umax - (e >> 6);              // longest first
    ts = 0;
    te = 2 * u + 2;
    pidx = 0;
    split = false;
  }
  const int q0 = u * 128;
  const int b = bh >> 5, h = bh & 31, g = h >> 2;
  const int tid = threadIdx.x;
  const int w = tid >> 6, lane = tid & 63;
  const int lc = lane & 31;        // q column (QK) / d column (PV)
  const int H  = lane >> 5;
  const int off4 = 4 * H;
  const int qw = q0 + w * 32;
  const int qg = qw + lc;          // this lane's q row (global)

  __shared__ bf16 k_lds[2][64 * 64];   // [kv][d], 16B-chunk XOR-swizzled
  __shared__ bf16 vt_lds[2][64 * 64];  // V^T [d][kv], chunk-swizzled (from vtg)

  // Q B-frag: col=q=lc, k(d) = 16s + 8H + j
  bf16x8 qf[4];
  {
    const bf16* qrow = q + (size_t)(b * L + qg) * QS + h * 64 + 8 * H;
#pragma unroll
    for (int s = 0; s < 4; ++s) qf[s] = *(const bf16x8*)(qrow + 16 * s);
  }

  f32x16 acc0, acc1;
#pragma unroll
  for (int r = 0; r < 16; ++r) { acc0[r] = 0.f; acc1[r] = 0.f; }
  float m_run = -1e30f, l_run = 0.f;

  const bf16* vbase = vtg + (size_t)(b * 8 + g) * 64 * L;

  auto stageK = [&](int kv0, int buf) {
#pragma unroll
    for (int i = 0; i < 2; ++i) {
      int c = tid + 256 * i;
      int kvr = c >> 3, c8 = c & 7;
      GLDS16(k + (size_t)(b * L + kv0 + kvr) * QS + g * 64 + ((c8 ^ (kvr & 7)) * 8),
             &k_lds[buf][(w * 64 + 256 * i) * 8]);
    }
  };
  auto stageV = [&](int kv0, int buf) {
#pragma unroll
    for (int i = 0; i < 2; ++i) {
      int c = tid + 256 * i;
      GLDS16(vbase + (size_t)(c >> 3) * L + kv0 + (c & 7) * 8,
             &vt_lds[buf][(w * 64 + 256 * i) * 8]);
    }
  };

  stageK(ts * 64, 0);
  stageV(ts * 64, 0);
  __syncthreads();

  for (int it = ts; it < te; ++it) {
    const int cur = (it - ts) & 1;
    const int kv0 = it * 64;
    const bool notlast = (it + 1 < te);
    if (notlast) {
      stageK(kv0 + 64, cur ^ 1);
      stageV(kv0 + 64, cur ^ 1);
    }

    if (kv0 <= qw + 31) {   // wave-uniform skip of fully-masked tiles
      // ---- S = K Q (A=K rows=kv, B=Q cols=q), exp2 domain ----
      f32x16 p0, p1;
#pragma unroll
      for (int r = 0; r < 16; ++r) { p0[r] = 0.f; p1[r] = 0.f; }
      __builtin_amdgcn_s_setprio(1);
#pragma unroll
      for (int s = 0; s < 4; ++s) {
        int ch = ((2 * s + H) ^ (lc & 7)) * 8;
        bf16x8 kf0 = *(const bf16x8*)&k_lds[cur][lc * 64 + ch];
        bf16x8 kf1 = *(const bf16x8*)&k_lds[cur][(32 + lc) * 64 + ch];
        p0 = MFMA32(kf0, qf[s], p0);
        p1 = MFMA32(kf1, qf[s], p1);
      }
      __builtin_amdgcn_s_setprio(0);

      // ---- causal mask: D row=kv=(r&3)+8(r>>2)+4H, col=q=lc ----
      if (kv0 + 63 > qw) {
#pragma unroll
        for (int r = 0; r < 16; ++r) {
          int kvl = kv0 + (r & 3) + 8 * (r >> 2) + off4;
          if (kvl > qg)      p0[r] = -1e30f;
          if (kvl + 32 > qg) p1[r] = -1e30f;
        }
      }

      // ---- online softmax, in-register (T12) + defer-max (T13) ----
      float mt = -1e30f;
#pragma unroll
      for (int r = 0; r < 16; ++r) mt = fmaxf(mt, fmaxf(p0[r], p1[r]));
      mt = fmaxf(mt, __shfl_xor(mt, 32));
      const int defer = __all(mt <= m_run + 11.0f);   // ~8 nats in log2 domain
      float alpha = 1.f;
      if (!defer) {
        float mn = fmaxf(m_run, mt);
        alpha = exp2f(m_run - mn);
        m_run = mn;
      }
      float ls = 0.f;
#pragma unroll
      for (int r = 0; r < 16; ++r) {
        p0[r] = exp2f(p0[r] - m_run);
        p1[r] = exp2f(p1[r] - m_run);
        ls += p0[r] + p1[r];
      }
      ls += __shfl_xor(ls, 32);
      l_run = l_run * alpha + ls;
      if (!defer) {
#pragma unroll
        for (int r = 0; r < 16; ++r) {
          float aq = __shfl(alpha, ((r & 3) + 8 * (r >> 2)) + off4);
          acc0[r] *= aq;
          acc1[r] *= aq;
        }
      }

      // ---- P -> bf16 A-frags: pack pairs, permlane32_swap redistributes ----
      unsigned A[16];
#pragma unroll
      for (int i = 0; i < 8; ++i) {
        A[i]     = pk2(p0[2 * i], p0[2 * i + 1]);
        A[8 + i] = pk2(p1[2 * i], p1[2 * i + 1]);
      }
#pragma unroll
      for (int base = 0; base < 16; base += 4) {
        PLSWAP(A[base],     A[base + 2]);
        PLSWAP(A[base + 1], A[base + 3]);
      }

      // ---- O += P V  (A=P rows=q, B=V^T cols=d) ----
      __builtin_amdgcn_s_setprio(1);
#pragma unroll
      for (int sp = 0; sp < 4; ++sp) {
        union { unsigned u[4]; bf16x8 v8; } pa;
#pragma unroll
        for (int jx = 0; jx < 4; ++jx) pa.u[jx] = A[4 * sp + jx];
        int ch = ((2 * sp + H) ^ (lc & 7)) * 8;
        bf16x8 vf0 = *(const bf16x8*)&vt_lds[cur][lc * 64 + ch];
        bf16x8 vf1 = *(const bf16x8*)&vt_lds[cur][(32 + lc) * 64 + ch];
        acc0 = MFMA32(pa.v8, vf0, acc0);
        acc1 = MFMA32(pa.v8, vf1, acc1);
      }
      __builtin_amdgcn_s_setprio(0);
    }

    __syncthreads();   // drains prefetch vmcnt; publishes next buffers
  }

  if (split) {
    // ---- unnormalized partial store: O~ (bf16), m/l (f32, lanes H==0) ----
    bf16* op = opart + (size_t)pidx * (128 * 64);
#pragma unroll
    for (int r = 0; r < 16; ++r) {
      int qrow = w * 32 + (r & 3) + 8 * (r >> 2) + off4;
      op[qrow * 64 + lc]      = (bf16)acc0[r];
      op[qrow * 64 + 32 + lc] = (bf16)acc1[r];
    }
    if (H == 0) {
      mpart[(size_t)pidx * 128 + w * 32 + lc] = m_run;
      lpart[(size_t)pidx * 128 + w * 32 + lc] = l_run;
    }
  } else {
    // ---- normalized store ----
#pragma unroll
    for (int r = 0; r < 16; ++r) {
      int qrow = (r & 3) + 8 * (r >> 2) + off4;
      float lq = __shfl(l_run, qrow);
      float inv = 1.f / lq;
      size_t orow = (size_t)(b * L + qw + qrow) * OS + h * 64;
      o[orow + lc]      = (bf16)(acc0[r] * inv);
      o[orow + 32 + lc] = (bf16)(acc1[r] * inv);
    }
  }
}

// ---------------- combine split-KV partials ----------------
// grid 576 = (bh 64) x (uu 9, u=uu+7); 256 thr: thread -> (row = t>>1, dh).
__global__ __launch_bounds__(256) void comb_kernel(const bf16* __restrict__ opart,
                                                   const float* __restrict__ mpart,
                                                   const float* __restrict__ lpart,
                                                   bf16* __restrict__ o) {
  constexpr int L = 2048, OS = 2048;
  const int blk = blockIdx.x;
  const int bh = blk / 9, uu = blk % 9, u = uu + 7;
  const int b = bh >> 5, h = bh & 31;
  const int q0 = u * 128;
  const int t = threadIdx.x;
  const int row = t >> 1, dh = (t & 1) * 32;

  const size_t s0 = (size_t)blk * 2, s1 = s0 + 1;
  float m0 = mpart[s0 * 128 + row], m1 = mpart[s1 * 128 + row];
  float l0 = lpart[s0 * 128 + row], l1 = lpart[s1 * 128 + row];
  float m = fmaxf(m0, m1);
  float w0 = exp2f(m0 - m), w1 = exp2f(m1 - m);
  float inv = 1.f / (l0 * w0 + l1 * w1);

  const bf16* O0 = opart + s0 * (128 * 64) + row * 64 + dh;
  const bf16* O1 = opart + s1 * (128 * 64) + row * 64 + dh;
  bf16* orow = o + (size_t)(b * L + q0 + row) * OS + h * 64 + dh;
#pragma unroll
  for (int j = 0; j < 4; ++j) {
    bf16x8 a = *(const bf16x8*)(O0 + 8 * j);
    bf16x8 c = *(const bf16x8*)(O1 + 8 * j);
    bf16x8 r;
#pragma unroll
    for (int e = 0; e < 8; ++e)
      r[e] = (bf16)(((float)a[e] * w0 + (float)c[e] * w1) * inv);
    *(bf16x8*)(orow + 8 * j) = r;
  }
}

extern "C" void kernel_launch(void* const* d_in, const int* in_sizes, int n_in,
                              void* d_out, int out_size, void* d_ws, size_t ws_size,
                              hipStream_t stream) {
  (void)in_sizes; (void)n_in; (void)out_size;
  const float* x    = (const float*)d_in[0];
  const float* cosb = (const float*)d_in[1];
  const float* sinb = (const float*)d_in[2];
  const float* Wq   = (const float*)d_in[3];
  const float* Wk   = (const float*)d_in[4];
  const float* Wv   = (const float*)d_in[5];
  const float* Wo   = (const float*)d_in[6];

  constexpr int B = 2, L = 2048, D = 2048, H = 32, G = 8;
  constexpr int M = B * L;           // 4096
  constexpr int DKV = G * 64;        // 512
  constexpr int NQKV = D + 2 * DKV;  // 3072

  char* p = (char*)d_ws;
  bf16*  xb   = (bf16*)p;  p += (size_t)M * D * 2;
  bf16*  wqkv = (bf16*)p;  p += (size_t)NQKV * D * 2;
  bf16*  wob  = (bf16*)p;  p += (size_t)D * D * 2;
  bf16*  qkv  = (bf16*)p;  p += (size_t)M * NQKV * 2;
  bf16*  vtg  = (bf16*)p;  p += (size_t)B * G * 64 * L * 2;
  bf16*  opart = (bf16*)p; p += (size_t)1152 * 128 * 64 * 2;
  float* mpart = (float*)p; p += (size_t)1152 * 128 * 4;
  float* lpart = (float*)p; p += (size_t)1152 * 128 * 4;
  bf16*  ob   = xb;  // xb dead after QKV GEMM

  const bool do_split = ws_size >= (size_t)(p - (char*)d_ws);

  cvt5_kernel<<<dim3(18432), 256, 0, stream>>>(x, Wq, Wk, Wv, Wo, xb, wqkv, wob);

  // fused QKV projection + RoPE epilogue (q scale = 0.125*log2e for exp2 softmax)
  gemm_bt<bf16, true><<<dim3(NQKV / 128, M / 128), 256, 0, stream>>>(
      xb, wqkv, qkv, M, NQKV, D, cosb, sinb);

  // V -> swizzled V^T global (consumed by attention via global_load_lds)
  vtr_kernel<<<dim3(L / 64, B * G), 256, 0, stream>>>(qkv + D + DKV, vtg);

  if (do_split) {
    attn_kernel<<<dim3(1600), 256, 0, stream>>>(qkv, qkv + D, vtg, ob,
                                                opart, mpart, lpart, 1152, 6);
    comb_kernel<<<dim3(576), 256, 0, stream>>>(opart, mpart, lpart, ob);
  } else {
    attn_kernel<<<dim3(1024), 256, 0, stream>>>(qkv, qkv + D, vtg, ob,
                                                opart, mpart, lpart, 0, 15);
  }

  gemm_bt<float, false><<<dim3(D / 128, M / 128), 256, 0, stream>>>(
      ob, wob, (float*)d_out, M, D, D, nullptr, nullptr);
}